// Round 3
// baseline (64.983 us; speedup 1.0000x reference)
//
#include <hip/hip_runtime.h>

// InterDistanceLossV2: masked relative pairwise-distance loss.
// loss = sum_b sum_ij m_i m_j |dp_ij - dt_ij| / (dt_ij + eps)  /  sum_b K_b^2
//
// R3: two-phase. Phase A compacts active points per batch (once) into ws as
// SoA; phase B is pure pair compute from compacted data (coalesced LDS fill,
// no per-block compaction), finished by a last-block ticket -> single output
// write. No separate reduce kernel, no memset dispatch.

constexpr int   NT     = 256;
constexpr int   NMAX   = 1024;        // max points per batch (N fixed = 1024)
constexpr int   ROWCH  = 32;          // row chunks per batch
constexpr int   HALVES = 2;           // column halves (512 compacted cols each)
constexpr int   SUBS   = ROWCH * HALVES;
constexpr int   RBLK   = 4;
constexpr float EPS    = 1e-8f;

// ws layout (float words)
constexpr int WS_NUM  = 0;            // float accumulator
constexpr int WS_DONE = 1;            // uint ticket counter
constexpr int WS_FCNT = 8;            // float K_b, [8, 8+256)
constexpr int WS_KCNT = 8 + 256;      // int K_b,  [264, 264+256)
constexpr int WS_DATA = 1024;         // per-batch SoA: 6 arrays x NMAX floats

__global__ __launch_bounds__(NT) void idl_compact(
    const float* __restrict__ preds, const float* __restrict__ targets,
    const int* __restrict__ mask, float* __restrict__ ws, int N)
{
    const int b = blockIdx.x, tid = threadIdx.x;
    const int wid = tid >> 6, lane = tid & 63;
    __shared__ int s_wt[NT / 64];
    __shared__ int s_base;

    if (tid == 0) s_base = 0;
    if (b == 0 && tid < 2) ws[tid] = 0.0f;   // zero num + ticket (bits of 0.0f == 0u)

    const int*   mb = mask    + (size_t)b * N;
    const float* pb = preds   + (size_t)b * N * 3;
    const float* tb = targets + (size_t)b * N * 3;
    float*       db = ws + WS_DATA + (size_t)b * 6 * NMAX;
    __syncthreads();

    for (int r = 0; r < N; r += NT) {
        const int  idx = r + tid;
        const bool act = (idx < N) && (mb[idx] != 0);
        const unsigned long long bal = __ballot(act);
        if (lane == 0) s_wt[wid] = (int)__popcll(bal);
        __syncthreads();
        int woff = s_base;
        for (int w = 0; w < wid; ++w) woff += s_wt[w];
        int total = 0;
#pragma unroll
        for (int w = 0; w < NT / 64; ++w) total += s_wt[w];
        if (act) {   // order-preserving: pos sorted by original index
            const int pos = woff + (int)__popcll(bal & ((1ull << lane) - 1ull));
            db[0 * NMAX + pos] = pb[idx * 3 + 0];
            db[1 * NMAX + pos] = pb[idx * 3 + 1];
            db[2 * NMAX + pos] = pb[idx * 3 + 2];
            db[3 * NMAX + pos] = tb[idx * 3 + 0];
            db[4 * NMAX + pos] = tb[idx * 3 + 1];
            db[5 * NMAX + pos] = tb[idx * 3 + 2];
        }
        __syncthreads();
        if (tid == 0) s_base += total;
        __syncthreads();
    }
    if (tid == 0) {
        const int K = s_base;
        ((int*)ws)[WS_KCNT + b] = K;
        ws[WS_FCNT + b] = (float)K;
    }
}

__global__ __launch_bounds__(NT) void idl_pairs(
    float* __restrict__ ws, float* __restrict__ out, int B, int nBlocks)
{
    const int bid = blockIdx.x;
    const int b   = bid / SUBS;
    const int sub = bid % SUBS;
    const int rc  = sub >> 1;       // row chunk  [0,32)
    const int h   = sub & 1;        // column half {0,1}
    const int tid = threadIdx.x;

    __shared__ float sx[512], sy[512], sz[512];   // compacted preds (cols)
    __shared__ float qx[512], qy[512], qz[512];   // compacted targets (cols)
    __shared__ float s_red[NT / 64];

    const int    K  = ((const int*)ws)[WS_KCNT + b];
    const float* db = ws + WS_DATA + (size_t)b * 6 * NMAX;

    const int c0 = h * 512;
    const int nc = max(min(c0 + 512, K) - c0, 0);
    for (int j = tid; j < nc; j += NT) {          // coalesced stride-1 fill
        sx[j] = db[0 * NMAX + c0 + j];
        sy[j] = db[1 * NMAX + c0 + j];
        sz[j] = db[2 * NMAX + c0 + j];
        qx[j] = db[3 * NMAX + c0 + j];
        qy[j] = db[4 * NMAX + c0 + j];
        qz[j] = db[5 * NMAX + c0 + j];
    }
    __syncthreads();

    const int rpc = (K + ROWCH - 1) / ROWCH;      // compacted rows per chunk
    const int r0  = rc * rpc;
    const int r1  = min(r0 + rpc, K);

    float acc = 0.0f;
    for (int rg = r0; rg < r1; rg += RBLK) {
        float rpx[RBLK], rpy[RBLK], rpz[RBLK];
        float rtx[RBLK], rty[RBLK], rtz[RBLK];
        bool  rv[RBLK];
#pragma unroll
        for (int k = 0; k < RBLK; ++k) {          // wave-uniform global reads
            const int rr = rg + k;
            rv[k] = rr < r1;
            const int i = rv[k] ? rr : r0;
            rpx[k] = db[0 * NMAX + i]; rpy[k] = db[1 * NMAX + i]; rpz[k] = db[2 * NMAX + i];
            rtx[k] = db[3 * NMAX + i]; rty[k] = db[4 * NMAX + i]; rtz[k] = db[5 * NMAX + i];
        }
        for (int j = tid; j < nc; j += NT) {
            const float jpx = sx[j], jpy = sy[j], jpz = sz[j];
            const float jtx = qx[j], jty = qy[j], jtz = qz[j];
#pragma unroll
            for (int k = 0; k < RBLK; ++k) {
                if (rv[k]) {                       // block-uniform predicate
                    float dx = jpx - rpx[k], dy = jpy - rpy[k], dz = jpz - rpz[k];
                    float dp = __builtin_amdgcn_sqrtf(fmaf(dx, dx, fmaf(dy, dy, dz * dz)));
                    float ex = jtx - rtx[k], ey = jty - rty[k], ez = jtz - rtz[k];
                    float dt = __builtin_amdgcn_sqrtf(fmaf(ex, ex, fmaf(ey, ey, ez * ez)));
                    acc = fmaf(fabsf(dp - dt), __builtin_amdgcn_rcpf(dt + EPS), acc);
                }
            }
        }
    }

    for (int off = 32; off > 0; off >>= 1) acc += __shfl_down(acc, off, 64);
    if ((tid & 63) == 0) s_red[tid >> 6] = acc;
    __syncthreads();
    if (tid == 0) {
        float s = 0.0f;
#pragma unroll
        for (int w = 0; w < NT / 64; ++w) s += s_red[w];
        atomicAdd(&ws[WS_NUM], s);                 // device-scope
        __threadfence();
        const unsigned t = atomicAdd((unsigned*)ws + WS_DONE, 1u);
        if (t == (unsigned)(nBlocks - 1)) {        // last block finalizes
            __threadfence();
            const float num = atomicAdd(&ws[WS_NUM], 0.0f);  // coherent read
            float den = 0.0f;
            for (int bb = 0; bb < B; ++bb) {
                const float c = ws[WS_FCNT + bb];
                den = fmaf(c, c, den);
            }
            out[0] = num / den;
        }
    }
}

// ---------- fallback (self-contained, needs only 8B of ws) ----------
__global__ __launch_bounds__(NT) void idl_fb(
    const float* __restrict__ preds, const float* __restrict__ targets,
    const int* __restrict__ mask, float* __restrict__ ws, int N)
{
    const int b     = blockIdx.x / 32;
    const int chunk = blockIdx.x % 32;
    __shared__ float spx[1024], spy[1024], spz[1024];
    __shared__ float stx[1024], sty[1024], stz[1024];
    __shared__ int   s_rows[32];
    __shared__ int   s_nrows, s_cnt;
    const float* pb = preds   + (size_t)b * N * 3;
    const float* tb = targets + (size_t)b * N * 3;
    const int*   mb = mask    + (size_t)b * N;
    const int tid = threadIdx.x;
    if (tid == 0) s_cnt = 0;
    __syncthreads();
    for (int j = tid; j < N; j += NT) {
        if (mb[j] != 0) {
            int p = atomicAdd(&s_cnt, 1);
            spx[p] = pb[j*3+0]; spy[p] = pb[j*3+1]; spz[p] = pb[j*3+2];
            stx[p] = tb[j*3+0]; sty[p] = tb[j*3+1]; stz[p] = tb[j*3+2];
        }
    }
    if (tid < 64) {
        bool act = (tid < 32) && (mb[chunk * 32 + tid] != 0);
        unsigned long long bal = __ballot(act);
        if (act) s_rows[__popcll(bal & ((1ull << tid) - 1ull))] = chunk * 32 + tid;
        if (tid == 0) s_nrows = (int)__popcll(bal);
    }
    __syncthreads();
    const int K = s_cnt, nrows = s_nrows;
    float acc = 0.0f;
    for (int rg = 0; rg < nrows; ++rg) {
        const int i = s_rows[rg];
        float rpx = pb[i*3+0], rpy = pb[i*3+1], rpz = pb[i*3+2];
        float rtx = tb[i*3+0], rty = tb[i*3+1], rtz = tb[i*3+2];
        for (int j = tid; j < K; j += NT) {
            float dx = spx[j]-rpx, dy = spy[j]-rpy, dz = spz[j]-rpz;
            float dp = __builtin_amdgcn_sqrtf(fmaf(dx,dx,fmaf(dy,dy,dz*dz)));
            float ex = stx[j]-rtx, ey = sty[j]-rty, ez = stz[j]-rtz;
            float dt = __builtin_amdgcn_sqrtf(fmaf(ex,ex,fmaf(ey,ey,ez*ez)));
            acc = fmaf(fabsf(dp-dt), __builtin_amdgcn_rcpf(dt + EPS), acc);
        }
    }
    for (int off = 32; off > 0; off >>= 1) acc += __shfl_down(acc, off, 64);
    if ((tid & 63) == 0) atomicAdd(&ws[0], acc);
    if (chunk == 0 && tid == 0) atomicAdd(&ws[1], (float)K * (float)K);
}
__global__ void idl_fb_final(const float* __restrict__ ws, float* __restrict__ out)
{ out[0] = ws[0] / ws[1]; }

extern "C" void kernel_launch(void* const* d_in, const int* in_sizes, int n_in,
                              void* d_out, int out_size, void* d_ws, size_t ws_size,
                              hipStream_t stream)
{
    const float* preds   = (const float*)d_in[0];
    const float* targets = (const float*)d_in[1];
    const int*   mask    = (const int*)d_in[2];
    const int N = 1024;                     // fixed by setup_inputs
    const int B = in_sizes[2] / N;
    float* ws = (float*)d_ws;

    const int    nBlocks = B * SUBS;
    const size_t need    = ((size_t)WS_DATA + (size_t)B * 6 * NMAX) * sizeof(float);

    if (ws_size >= need && B <= 256) {
        idl_compact<<<dim3(B),       NT, 0, stream>>>(preds, targets, mask, ws, N);
        idl_pairs  <<<dim3(nBlocks), NT, 0, stream>>>(ws, (float*)d_out, B, nBlocks);
    } else {
        hipMemsetAsync(ws, 0, 2 * sizeof(float), stream);
        idl_fb<<<dim3(B * 32), NT, 0, stream>>>(preds, targets, mask, ws, N);
        idl_fb_final<<<dim3(1), 1, 0, stream>>>(ws, (float*)d_out);
    }
}

// Round 4
// 18.173 us; speedup vs baseline: 3.5758x; 3.5758x over previous
//
#include <hip/hip_runtime.h>

// InterDistanceLossV2: masked relative pairwise-distance loss.
// loss = sum_b sum_ij m_i m_j |dp_ij - dt_ij| / (dt_ij + eps)  /  sum_b K_b^2
//
// R4: one fused block kernel. Each block ballot-scan-compacts its whole batch
// into LDS (no LDS atomics, no global atomics anywhere), computes its 1/32 of
// compacted rows against all K columns, writes one partial. Tiny finalize
// kernel reduces partials + counts. Atomic storms (R1/R3 lesson: ~50us for
// ~4096 same-address device atomics) are fully eliminated.

constexpr int   NT   = 256;
constexpr int   SUBS = 32;           // blocks per batch -> grid = 32*32 = 1024
constexpr int   RBLK = 4;
constexpr int   NMAX = 1024;         // max points per batch
constexpr float EPS  = 1e-8f;

__global__ __launch_bounds__(NT) void idl_block(
    const float* __restrict__ preds, const float* __restrict__ targets,
    const int* __restrict__ mask, float* __restrict__ partials,
    float* __restrict__ counts, int N)
{
    const int bid = blockIdx.x;
    const int b   = bid / SUBS;
    const int sub = bid % SUBS;
    const int tid = threadIdx.x;
    const int wid = tid >> 6, lane = tid & 63;

    __shared__ float px[NMAX], py[NMAX], pz[NMAX];   // compacted preds
    __shared__ float qx[NMAX], qy[NMAX], qz[NMAX];   // compacted targets
    __shared__ int   s_wt[NT / 64];
    __shared__ int   s_base;
    __shared__ float s_red[NT / 64];

    const float* pb = preds   + (size_t)b * N * 3;
    const float* tb = targets + (size_t)b * N * 3;
    const int*   mb = mask    + (size_t)b * N;

    if (tid == 0) s_base = 0;
    __syncthreads();

    // ---- ballot-scan compaction (order-preserving, zero atomics) ----
    for (int r = 0; r < N; r += NT) {
        const int  idx = r + tid;
        const bool act = (idx < N) && (mb[idx] != 0);
        float ppx = 0, ppy = 0, ppz = 0, ttx = 0, tty = 0, ttz = 0;
        if (act) {
            ppx = pb[idx * 3 + 0]; ppy = pb[idx * 3 + 1]; ppz = pb[idx * 3 + 2];
            ttx = tb[idx * 3 + 0]; tty = tb[idx * 3 + 1]; ttz = tb[idx * 3 + 2];
        }
        const unsigned long long bal = __ballot(act);
        if (lane == 0) s_wt[wid] = (int)__popcll(bal);
        __syncthreads();
        int off = s_base;
        for (int w = 0; w < wid; ++w) off += s_wt[w];
        int tot = 0;
#pragma unroll
        for (int w = 0; w < NT / 64; ++w) tot += s_wt[w];
        if (act) {
            const int pos = off + (int)__popcll(bal & ((1ull << lane) - 1ull));
            px[pos] = ppx; py[pos] = ppy; pz[pos] = ppz;
            qx[pos] = ttx; qy[pos] = tty; qz[pos] = ttz;
        }
        __syncthreads();
        if (tid == 0) s_base += tot;
        __syncthreads();
    }

    const int K   = s_base;
    const int rpc = (K + SUBS - 1) / SUBS;          // compacted rows per block
    const int r0  = min(sub * rpc, K);
    const int r1  = min(r0 + rpc, K);

    // ---- pair compute: rows [r0,r1) x cols [0,K), all from LDS ----
    float acc = 0.0f;
    for (int rg = r0; rg < r1; rg += RBLK) {
        float rpx[RBLK], rpy[RBLK], rpz[RBLK];
        float rtx[RBLK], rty[RBLK], rtz[RBLK];
        bool  rv[RBLK];
#pragma unroll
        for (int k = 0; k < RBLK; ++k) {            // uniform addr -> broadcast
            const int rr = rg + k;
            rv[k] = rr < r1;
            const int i = rv[k] ? rr : r0;
            rpx[k] = px[i]; rpy[k] = py[i]; rpz[k] = pz[i];
            rtx[k] = qx[i]; rty[k] = qy[i]; rtz[k] = qz[i];
        }
        for (int j = tid; j < K; j += NT) {
            const float jpx = px[j], jpy = py[j], jpz = pz[j];
            const float jtx = qx[j], jty = qy[j], jtz = qz[j];
#pragma unroll
            for (int k = 0; k < RBLK; ++k) {
                if (rv[k]) {                         // block-uniform predicate
                    float dx = jpx - rpx[k], dy = jpy - rpy[k], dz = jpz - rpz[k];
                    float dp = __builtin_amdgcn_sqrtf(fmaf(dx, dx, fmaf(dy, dy, dz * dz)));
                    float ex = jtx - rtx[k], ey = jty - rty[k], ez = jtz - rtz[k];
                    float dt = __builtin_amdgcn_sqrtf(fmaf(ex, ex, fmaf(ey, ey, ez * ez)));
                    acc = fmaf(fabsf(dp - dt), __builtin_amdgcn_rcpf(dt + EPS), acc);
                }
            }
        }
    }

    // ---- block reduce -> one non-atomic partial per block ----
    for (int off = 32; off > 0; off >>= 1) acc += __shfl_down(acc, off, 64);
    if ((tid & 63) == 0) s_red[tid >> 6] = acc;
    __syncthreads();
    if (tid == 0) {
        float s = 0.0f;
#pragma unroll
        for (int w = 0; w < NT / 64; ++w) s += s_red[w];
        partials[bid] = s;
        if (sub == 0) counts[b] = (float)K;
    }
}

__global__ __launch_bounds__(NT) void idl_final(
    const float* __restrict__ partials, int nP,
    const float* __restrict__ counts, int B, float* __restrict__ out)
{
    __shared__ float s_n[NT / 64], s_d[NT / 64];
    const int tid = threadIdx.x;
    float num = 0.0f, den = 0.0f;
    for (int i = tid; i < nP; i += NT) num += partials[i];
    for (int i = tid; i < B;  i += NT) { const float c = counts[i]; den = fmaf(c, c, den); }
    for (int off = 32; off > 0; off >>= 1) {
        num += __shfl_down(num, off, 64);
        den += __shfl_down(den, off, 64);
    }
    if ((tid & 63) == 0) { s_n[tid >> 6] = num; s_d[tid >> 6] = den; }
    __syncthreads();
    if (tid == 0) {
        float n = 0.0f, d = 0.0f;
#pragma unroll
        for (int w = 0; w < NT / 64; ++w) { n += s_n[w]; d += s_d[w]; }
        out[0] = n / d;
    }
}

extern "C" void kernel_launch(void* const* d_in, const int* in_sizes, int n_in,
                              void* d_out, int out_size, void* d_ws, size_t ws_size,
                              hipStream_t stream)
{
    const float* preds   = (const float*)d_in[0];
    const float* targets = (const float*)d_in[1];
    const int*   mask    = (const int*)d_in[2];
    const int N = 1024;                       // fixed by setup_inputs (B=32, N=1024, D=3)
    const int B = in_sizes[2] / N;
    float* ws = (float*)d_ws;

    const int nBlocks = B * SUBS;
    float* partials = ws;                     // [nBlocks] — every block writes its slot
    float* counts   = ws + nBlocks;           // [B]       — every batch's sub==0 writes

    idl_block<<<dim3(nBlocks), NT, 0, stream>>>(preds, targets, mask, partials, counts, N);
    idl_final<<<dim3(1), NT, 0, stream>>>(partials, nBlocks, counts, B, (float*)d_out);
}

// Round 5
// 16.698 us; speedup vs baseline: 3.8918x; 1.0884x over previous
//
#include <hip/hip_runtime.h>

// InterDistanceLossV2: masked relative pairwise-distance loss.
// loss = sum_b sum_ij m_i m_j |dp_ij - dt_ij| / (dt_ij + eps)  /  sum_b K_b^2
//
// R5: triangular chunked pair kernel.
//  - Each block ballot-scan-compacts its whole batch into LDS (2 syncs, no atomics).
//  - C=8 chunks; block (a,b), a<=b, computes rect chunk_a x chunk_b; off-diag
//    rectangles weighted x2 (symmetry) -> 0.56x the pair-steps of full matrix.
//  - Cols held in registers (lane = col), rows read 4-at-a-time via ds_read_b128
//    (chunk starts 4-aligned).
//  - rsq formulation: term = |dp - st*rsq(st)| * rsq(st), guarded (st>0).
//  - No global atomics: partials + counts, tiny finalize kernel.

constexpr int NT   = 256;
constexpr int C    = 8;                 // chunks per batch
constexpr int TRI  = C * (C + 1) / 2;   // 36 blocks per batch
constexpr int NMAX = 1024;

__global__ __launch_bounds__(NT) void idl_tri(
    const float* __restrict__ preds, const float* __restrict__ targets,
    const int* __restrict__ mask, float* __restrict__ partials,
    float* __restrict__ counts)
{
    const int bid = blockIdx.x;
    const int b   = bid / TRI;
    int ca = 0, cb;
    {   // sub -> (ca, cb) triangle coords, ca <= cb
        int s = bid % TRI, rem = C;
        while (s >= rem) { s -= rem; --rem; ++ca; }
        cb = ca + s;
    }
    const int tid  = threadIdx.x;
    const int wid  = tid >> 6, lane = tid & 63;
    const int N    = 1024;              // fixed by setup_inputs

    __shared__ __align__(16) float px[NMAX], py[NMAX], pz[NMAX];
    __shared__ __align__(16) float qx[NMAX], qy[NMAX], qz[NMAX];
    __shared__ int   s_wt[4][4];
    __shared__ float s_red[4];

    const float* pb = preds   + (size_t)b * N * 3;
    const float* tb = targets + (size_t)b * N * 3;
    const int*   mb = mask    + (size_t)b * N;

    // ---- compaction: all mask loads + ballots upfront, 2 syncs total ----
    int msk[4];
#pragma unroll
    for (int s = 0; s < 4; ++s) msk[s] = mb[s * NT + tid];
    unsigned long long bal[4];
#pragma unroll
    for (int s = 0; s < 4; ++s) bal[s] = __ballot(msk[s] != 0);
    if (lane == 0) {
#pragma unroll
        for (int s = 0; s < 4; ++s) s_wt[s][wid] = (int)__popcll(bal[s]);
    }
    __syncthreads();

    int base[4], run = 0;
#pragma unroll
    for (int s = 0; s < 4; ++s) {
#pragma unroll
        for (int w = 0; w < 4; ++w) {
            if (w == wid) base[s] = run;
            run += s_wt[s][w];
        }
    }
    const int K = run;

    const unsigned long long lt = (1ull << lane) - 1ull;
#pragma unroll
    for (int s = 0; s < 4; ++s) {
        if (msk[s]) {
            const int idx = s * NT + tid;
            const int pos = base[s] + (int)__popcll(bal[s] & lt);
            px[pos] = pb[idx * 3 + 0]; py[pos] = pb[idx * 3 + 1]; pz[pos] = pb[idx * 3 + 2];
            qx[pos] = tb[idx * 3 + 0]; qy[pos] = tb[idx * 3 + 1]; qz[pos] = tb[idx * 3 + 2];
        }
    }
    __syncthreads();

    // ---- chunk geometry (chunk size multiple of 4 -> b128-aligned rows) ----
    const int ch  = 4 * ((K + 4 * C - 1) / (4 * C));
    const int ra0 = min(ca * ch, K), ra1 = min(ra0 + ch, K);
    const int cb0 = min(cb * ch, K), cb1 = min(cb0 + ch, K);
    const int csz = cb1 - cb0;
    const int rsz = ra1 - ra0;

    const int rq = 4 * ((rsz + 15) / 16);        // rows per wave (multiple of 4)
    const int r0 = ra0 + wid * rq;
    const int r1 = min(r0 + rq, ra1);

    float acc = 0.0f;
    for (int cp = 0; cp * 64 < csz; ++cp) {
        const int  jr = cp * 64 + lane;
        const bool jv = jr < csz;
        const int  j  = cb0 + (jv ? jr : 0);
        const float jpx = px[j], jpy = py[j], jpz = pz[j];
        const float jtx = qx[j], jty = qy[j], jtz = qz[j];

        for (int rg = r0; rg < r1; rg += 4) {
            const float4 r4x = *(const float4*)&px[rg];
            const float4 r4y = *(const float4*)&py[rg];
            const float4 r4z = *(const float4*)&pz[rg];
            const float4 s4x = *(const float4*)&qx[rg];
            const float4 s4y = *(const float4*)&qy[rg];
            const float4 s4z = *(const float4*)&qz[rg];
            const float rxa[4] = {r4x.x, r4x.y, r4x.z, r4x.w};
            const float rya[4] = {r4y.x, r4y.y, r4y.z, r4y.w};
            const float rza[4] = {r4z.x, r4z.y, r4z.z, r4z.w};
            const float sxa[4] = {s4x.x, s4x.y, s4x.z, s4x.w};
            const float sya[4] = {s4y.x, s4y.y, s4y.z, s4y.w};
            const float sza[4] = {s4z.x, s4z.y, s4z.z, s4z.w};
            const int nk = r1 - rg;
#pragma unroll
            for (int k = 0; k < 4; ++k) {
                if (k < nk) {                      // wave-uniform
                    const float dx = jpx - rxa[k], dy = jpy - rya[k], dz = jpz - rza[k];
                    const float sp = fmaf(dx, dx, fmaf(dy, dy, dz * dz));
                    const float dp = __builtin_amdgcn_sqrtf(sp);
                    const float ex = jtx - sxa[k], ey = jty - sya[k], ez = jtz - sza[k];
                    const float st = fmaf(ex, ex, fmaf(ey, ey, ez * ez));
                    const float rr = __builtin_amdgcn_rsqf(st);
                    const float dt = st * rr;                 // sqrt(st); NaN at st=0
                    const float t  = fabsf(dp - dt) * rr;     // |dp-dt|/dt
                    acc += (jv && st > 0.0f) ? t : 0.0f;      // guard kills NaN + diag
                }
            }
        }
    }

    // ---- block reduce -> one partial per block (x2 for off-diagonal) ----
    for (int off = 32; off > 0; off >>= 1) acc += __shfl_down(acc, off, 64);
    if (lane == 0) s_red[wid] = acc;
    __syncthreads();
    if (tid == 0) {
        float ssum = s_red[0] + s_red[1] + s_red[2] + s_red[3];
        if (ca != cb) ssum *= 2.0f;
        partials[bid] = ssum;
        if (ca == 0 && cb == 0) counts[b] = (float)K;
    }
}

__global__ __launch_bounds__(NT) void idl_final(
    const float* __restrict__ partials, int nP,
    const float* __restrict__ counts, int B, float* __restrict__ out)
{
    __shared__ float s_n[NT / 64], s_d[NT / 64];
    const int tid = threadIdx.x;
    float num = 0.0f, den = 0.0f;
    for (int i = tid; i < nP; i += NT) num += partials[i];
    for (int i = tid; i < B;  i += NT) { const float c = counts[i]; den = fmaf(c, c, den); }
    for (int off = 32; off > 0; off >>= 1) {
        num += __shfl_down(num, off, 64);
        den += __shfl_down(den, off, 64);
    }
    if ((tid & 63) == 0) { s_n[tid >> 6] = num; s_d[tid >> 6] = den; }
    __syncthreads();
    if (tid == 0) {
        float n = 0.0f, d = 0.0f;
#pragma unroll
        for (int w = 0; w < NT / 64; ++w) { n += s_n[w]; d += s_d[w]; }
        out[0] = n / d;
    }
}

extern "C" void kernel_launch(void* const* d_in, const int* in_sizes, int n_in,
                              void* d_out, int out_size, void* d_ws, size_t ws_size,
                              hipStream_t stream)
{
    const float* preds   = (const float*)d_in[0];
    const float* targets = (const float*)d_in[1];
    const int*   mask    = (const int*)d_in[2];
    const int N = 1024;                       // fixed by setup_inputs (B=32, N=1024, D=3)
    const int B = in_sizes[2] / N;

    float* ws       = (float*)d_ws;
    const int nBlocks = B * TRI;
    float* partials = ws;                     // [nBlocks] — every block writes its slot
    float* counts   = ws + nBlocks;           // [B]       — block (0,0) of each batch writes

    idl_tri  <<<dim3(nBlocks), NT, 0, stream>>>(preds, targets, mask, partials, counts);
    idl_final<<<dim3(1),       NT, 0, stream>>>(partials, nBlocks, counts, B, (float*)d_out);
}